// Round 8
// baseline (248.311 us; speedup 1.0000x reference)
//
#include <hip/hip_runtime.h>
#include <hip/hip_cooperative_groups.h>
#include <math.h>

#define EPSV 1e-5f

namespace cg = cooperative_groups;

static constexpr int Ls = 2048, Hh = 8;
static constexpr int NCH = 64, T = 32;   // 64 chunks of 32 along L

typedef unsigned short u16;
using frag  = __attribute__((ext_vector_type(8))) short;   // 8 x bf16 (4 VGPRs)
using f32x4 = __attribute__((ext_vector_type(4))) float;

__device__ __forceinline__ void split_bf16(float v, u16& hi, u16& lo) {
    const unsigned u = __float_as_uint(v);
    hi = (u16)(u >> 16);
    const float hf = __uint_as_float((unsigned)hi << 16);
    lo = (u16)(__float_as_uint(v - hf) >> 16);
}

__device__ __forceinline__ unsigned pk2(u16 a, u16 b) {
    return (unsigned)a | ((unsigned)b << 16);
}

__device__ __forceinline__ void split8(const float4& a, const float4& b,
                                       uint4& hi, uint4& lo) {
    u16 h[8], l[8];
    const float f[8] = {a.x, a.y, a.z, a.w, b.x, b.y, b.z, b.w};
#pragma unroll
    for (int i = 0; i < 8; ++i) split_bf16(f[i], h[i], l[i]);
    hi = make_uint4(pk2(h[0], h[1]), pk2(h[2], h[3]), pk2(h[4], h[5]), pk2(h[6], h[7]));
    lo = make_uint4(pk2(l[0], l[1]), pk2(l[2], l[3]), pk2(l[4], l[5]), pk2(l[6], l[7]));
}

struct Params {
    const float *x, *wq, *wk, *wv, *bq, *bk, *bv, *wo, *bo, *wg_w, *wg_b, *kvs, *qks;
    float *qh, *kh, *vh, *simG, *gG, *ZcT, *mT, *sT, *gTt, *aW, *bW;
    int* flagW;
    u16 *chi, *clo;
    float* out;
};

// phase = -1: all phases with grid.sync (cooperative). phase = 0..3: that phase only.
__global__ __launch_bounds__(256) void mega_kernel(Params p, int phase) {
    // union shared memory: max over phases = qkv phase, 15616 floats (62.4 KB)
    __shared__ __align__(16) float smem[15616];

    const int tid = threadIdx.x;
    const int bid = blockIdx.x;
    const int wave = tid >> 6, lane = tid & 63;
    const int l15 = lane & 15, quad = lane >> 4;

    // ================= phase 0: qkv split-bf16 MFMA GEMM + chunk_sum ==========
    if (phase < 0 || phase == 0) {
        constexpr int LDK = 40;     // u16 per staged row
        constexpr int LDT = 68;     // f32 per tile row (272 B, float4-aligned)
        u16* As_hi = (u16*)smem;           // 2560 u16
        u16* As_lo = As_hi + 2560;
        u16* Wst   = As_lo + 2560;         // weight w: hi at w*5120, lo +2560
        float* Qt = smem;
        float* Kt = Qt + 64 * LDT;
        float* Vt = Kt + 64 * LDT;
        float* wkT  = smem + 13056;        // [h][e*36+d], 2304 f
        float* lsim = smem + 15360;        // [h][l], 128 f
        float* lg2  = smem + 15488;        // [h][l], 128 f

        const int mt = bid & 63, nt = bid >> 6;
        const int m0 = mt * 64, ncol0 = nt * 64;
        const int bidx = m0 >> 11, lg = m0 & (Ls - 1);
        const int srow = tid >> 2, sk = (tid & 3) * 8;

        for (int i = tid; i < 2048; i += 256) {
            const int h = i >> 10, de = i & 1023;
            const int d = de >> 5, e = de & 31;
            wkT[h * 1152 + e * 36 + d] = p.wg_w[de] * p.kvs[(nt * 2 + h) * 1024 + de];
        }

        const float* Wsrc[3] = {p.wq, p.wk, p.wv};
        f32x4 acc[3][4] = {};

        for (int k0 = 0; k0 < 256; k0 += 32) {
            const float4 a0 = *(const float4*)&p.x[(size_t)(m0 + srow) * 256 + k0 + sk];
            const float4 a1 = *(const float4*)&p.x[(size_t)(m0 + srow) * 256 + k0 + sk + 4];
            float4 w0[3], w1[3];
#pragma unroll
            for (int w = 0; w < 3; ++w) {
                w0[w] = *(const float4*)&Wsrc[w][(size_t)(ncol0 + srow) * 256 + k0 + sk];
                w1[w] = *(const float4*)&Wsrc[w][(size_t)(ncol0 + srow) * 256 + k0 + sk + 4];
            }
            __syncthreads();
            {
                uint4 hi, lo;
                split8(a0, a1, hi, lo);
                *(uint4*)&As_hi[srow * LDK + sk] = hi;
                *(uint4*)&As_lo[srow * LDK + sk] = lo;
#pragma unroll
                for (int w = 0; w < 3; ++w) {
                    split8(w0[w], w1[w], hi, lo);
                    *(uint4*)&Wst[w * 5120 + srow * LDK + sk] = hi;
                    *(uint4*)&Wst[w * 5120 + 2560 + srow * LDK + sk] = lo;
                }
            }
            __syncthreads();

            frag ah[4], al[4];
#pragma unroll
            for (int tm = 0; tm < 4; ++tm) {
                const int r = tm * 16 + l15;
                ah[tm] = *(const frag*)&As_hi[r * LDK + quad * 8];
                al[tm] = *(const frag*)&As_lo[r * LDK + quad * 8];
            }
#pragma unroll
            for (int w = 0; w < 3; ++w) {
                const u16* bp = &Wst[w * 5120 + (wave * 16 + l15) * LDK + quad * 8];
                const frag bh = *(const frag*)bp;
                const frag bl = *(const frag*)(bp + 2560);
#pragma unroll
                for (int tm = 0; tm < 4; ++tm) {
                    acc[w][tm] = __builtin_amdgcn_mfma_f32_16x16x32_bf16(ah[tm], bh, acc[w][tm], 0, 0, 0);
                    acc[w][tm] = __builtin_amdgcn_mfma_f32_16x16x32_bf16(ah[tm], bl, acc[w][tm], 0, 0, 0);
                    acc[w][tm] = __builtin_amdgcn_mfma_f32_16x16x32_bf16(al[tm], bh, acc[w][tm], 0, 0, 0);
                }
            }
        }
        __syncthreads();   // staging dead; write tiles (aliased region)

        {
            float* tiles[3] = {Qt, Kt, Vt};
            const float* biases[3] = {p.bq, p.bk, p.bv};
#pragma unroll
            for (int w = 0; w < 3; ++w) {
                const int col = wave * 16 + l15;
                const float bias = biases[w][ncol0 + col];
#pragma unroll
                for (int tm = 0; tm < 4; ++tm)
#pragma unroll
                    for (int r = 0; r < 4; ++r) {
                        const int m = tm * 16 + quad * 4 + r;
                        tiles[w][m * LDT + col] = acc[w][tm][r] + bias;
                    }
            }
        }
        __syncthreads();

        // ---- Phase N: normalize k,v in place; sim ----
        if (tid < 128) {
            const int h = tid >> 6, l = tid & 63;
            const int rb = l * LDT + h * 32;
            float4 kr[8], vr[8];
            float ksum = 0.f, vsum = 0.f, qk = 0.f;
#pragma unroll
            for (int e4 = 0; e4 < 8; ++e4) {
                kr[e4] = *(const float4*)&Kt[rb + e4 * 4];
                vr[e4] = *(const float4*)&Vt[rb + e4 * 4];
                const float4 q4 = *(const float4*)&Qt[rb + e4 * 4];
                ksum += kr[e4].x * kr[e4].x + kr[e4].y * kr[e4].y + kr[e4].z * kr[e4].z + kr[e4].w * kr[e4].w;
                vsum += vr[e4].x * vr[e4].x + vr[e4].y * vr[e4].y + vr[e4].z * vr[e4].z + vr[e4].w * vr[e4].w;
                qk   += q4.x * kr[e4].x + q4.y * kr[e4].y + q4.z * kr[e4].z + q4.w * kr[e4].w;
            }
            const float kscale = 1.f / fmaxf(sqrtf(ksum), 1e-12f);
            const float vscale = 1.f / fmaxf(sqrtf(vsum), 1e-12f);
#pragma unroll
            for (int e4 = 0; e4 < 8; ++e4) {
                float4 k4 = kr[e4], v4 = vr[e4];
                k4.x *= kscale; k4.y *= kscale; k4.z *= kscale; k4.w *= kscale;
                v4.x *= vscale; v4.y *= vscale; v4.z *= vscale; v4.w *= vscale;
                *(float4*)&Kt[rb + e4 * 4] = k4;
                *(float4*)&Vt[rb + e4 * 4] = v4;
            }
            const float sim = qk * p.qks[nt * 2 + h];
            lsim[h * 64 + l] = sim;
            p.simG[(size_t)(bidx * 8 + nt * 2 + h) * Ls + lg + l] = sim;
        }
        __syncthreads();

        // ---- copy q, kn, vn to global ----
        {
            const float* tl[3] = {Qt, Kt, Vt};
            float* gl[3] = {p.qh, p.kh, p.vh};
#pragma unroll
            for (int arr = 0; arr < 3; ++arr)
#pragma unroll
                for (int it = 0; it < 4; ++it) {
                    const int idx = it * 1024 + tid * 4;
                    const int h = idx >> 11, rem = idx & 2047;
                    const int l = rem >> 5, e4 = rem & 31;
                    const float4 v = *(const float4*)&tl[arr][l * LDT + h * 32 + e4];
                    *(float4*)&gl[arr][(size_t)(bidx * 8 + nt * 2 + h) * 65536 +
                                       (size_t)(lg + l) * 32 + e4] = v;
                }
        }

        // ---- Phase G: gate per (h,l); 2 threads per task ----
        {
            const int task = tid >> 1, half = tid & 1;
            const int h = task >> 6, l = task & 63;
            float4 vr[8];
#pragma unroll
            for (int d4 = 0; d4 < 8; ++d4)
                vr[d4] = *(const float4*)&Vt[l * LDT + h * 32 + d4 * 4];
            float u = 0.f;
            const int e0 = half * 16;
#pragma unroll 4
            for (int e = e0; e < e0 + 16; ++e) {
                float4 s4 = make_float4(0.f, 0.f, 0.f, 0.f);
#pragma unroll
                for (int d4 = 0; d4 < 8; ++d4) {
                    const float4 w4 = *(const float4*)&wkT[h * 1152 + e * 36 + d4 * 4];
                    s4.x = fmaf(vr[d4].x, w4.x, s4.x);
                    s4.y = fmaf(vr[d4].y, w4.y, s4.y);
                    s4.z = fmaf(vr[d4].z, w4.z, s4.z);
                    s4.w = fmaf(vr[d4].w, w4.w, s4.w);
                }
                u = fmaf(s4.x + s4.y + s4.z + s4.w, Kt[l * LDT + h * 32 + e], u);
            }
            u += __shfl_xor(u, 1);
            if (half == 0) {
                const float r = fmaxf(u + p.wg_b[0], 0.f);
                const float g = r * r + EPSV;
                lg2[h * 64 + l] = g;
                p.gG[(size_t)(bidx * 8 + nt * 2 + h) * Ls + lg + l] = g;
            }
        }
        __syncthreads();

        // ---- Phase Z: chunk-Z totals ----
        {
            const int d = tid >> 3, e4m = (tid & 7) * 4;
#pragma unroll
            for (int h = 0; h < 2; ++h)
#pragma unroll
                for (int cc = 0; cc < 2; ++cc) {
                    float4 z4 = make_float4(0.f, 0.f, 0.f, 0.f);
#pragma unroll 8
                    for (int l = 0; l < 32; ++l) {
                        const int lr = cc * 32 + l;
                        const float gv = lg2[h * 64 + lr] * Vt[lr * LDT + h * 32 + d];
                        const float4 k4 = *(const float4*)&Kt[lr * LDT + h * 32 + e4m];
                        z4.x = fmaf(gv, k4.x, z4.x);
                        z4.y = fmaf(gv, k4.y, z4.y);
                        z4.z = fmaf(gv, k4.z, z4.z);
                        z4.w = fmaf(gv, k4.w, z4.w);
                    }
                    const int bhg = bidx * 8 + nt * 2 + h;
                    const int cg = (lg >> 5) + cc;
                    *(float4*)&p.ZcT[((size_t)bhg * NCH + cg) * 1024 + d * 32 + e4m] = z4;
                }
        }

        // ---- (m,s,g) chunk totals ----
        {
            const int h = wave >> 1, cc = wave & 1;
            if (lane < 32) {
                const int lr = cc * 32 + lane;
                float m = lsim[h * 64 + lr], s = 1.f, g = lg2[h * 64 + lr];
#pragma unroll
                for (int off = 16; off; off >>= 1) {
                    const float mo = __shfl_xor(m, off);
                    const float so = __shfl_xor(s, off);
                    const float mn = fmaxf(m, mo);
                    s = s * __expf(m - mn) + so * __expf(mo - mn);
                    m = mn;
                    g += __shfl_xor(g, off);
                }
                if (lane == 0) {
                    const int bhg = bidx * 8 + nt * 2 + h;
                    const int cg = (lg >> 5) + cc;
                    p.mT[bhg * NCH + cg] = m;
                    p.sT[bhg * NCH + cg] = s;
                    p.gTt[bhg * NCH + cg] = g;
                }
            }
        }
    }

    if (phase < 0) cg::this_grid().sync();

    // ================= phase A: prefix scans + rank-1 setup ===================
    if (phase < 0 || phase == 1) {
        float* sc = smem;   // 4096 f
        const int bh = bid >> 4, seg = bid & 15;
        float* Zb = p.ZcT + (size_t)bh * NCH * 1024 + seg * 64;

#pragma unroll
        for (int it = 0; it < 16; ++it) {
            const int idx = it * 256 + tid;
            const int cc = idx >> 6, e = idx & 63;
            sc[idx] = Zb[(size_t)cc * 1024 + e];
        }
        __syncthreads();
#pragma unroll
        for (int st = 1; st < 64; st <<= 1) {
            float tmp[16];
#pragma unroll
            for (int it = 0; it < 16; ++it) {
                const int idx = it * 256 + tid;
                tmp[it] = ((idx >> 6) >= st) ? sc[idx - st * 64] : 0.f;
            }
            __syncthreads();
#pragma unroll
            for (int it = 0; it < 16; ++it) sc[it * 256 + tid] += tmp[it];
            __syncthreads();
        }
#pragma unroll
        for (int it = 0; it < 16; ++it) {
            const int idx = it * 256 + tid;
            const int cc = idx >> 6, e = idx & 63;
            Zb[(size_t)cc * 1024 + e] = cc ? sc[idx - 64] : 0.f;   // exclusive
        }

        if (seg == 0 && tid < 64) {
            float m = p.mT[bh * NCH + tid], s = p.sT[bh * NCH + tid], g = p.gTt[bh * NCH + tid];
#pragma unroll
            for (int off = 1; off < 64; off <<= 1) {
                const float mo = __shfl_up(m, off);
                const float so = __shfl_up(s, off);
                const float go = __shfl_up(g, off);
                if (tid >= off) {
                    const float mn = fmaxf(m, mo);
                    s = s * __expf(m - mn) + so * __expf(mo - mn);
                    m = mn;
                    g += go;
                }
            }
            float me = __shfl_up(m, 1), se = __shfl_up(s, 1), ge = __shfl_up(g, 1);
            if (tid == 0) { me = -1e30f; se = 0.f; ge = 0.f; }
            p.mT[bh * NCH + tid] = me;
            p.sT[bh * NCH + tid] = se;
            p.gTt[bh * NCH + tid] = ge;
        }

        if (bid == 1) {   // bh==0, seg==1: rank-1 detection
            const int h = tid >> 5, e = tid & 31;
            const float* K = p.kvs + h * 1024;
            const float k00 = K[0];
            int ok = (k00 != 0.0f);
            for (int d = 0; d < 32; ++d) {
                const float lhs = K[d * 32 + e] * k00;
                const float rhs = K[d * 32] * K[e];
                const float diff = fabsf(lhs - rhs);
                if (diff > 1e-6f * fmaxf(fmaxf(fabsf(lhs), fabsf(rhs)), 1e-20f)) ok = 0;
            }
            p.aW[h * 32 + e] = K[e * 32];
            p.bW[h * 32 + e] = (k00 != 0.0f) ? K[e] / k00 : 0.f;
            const int allok = __syncthreads_and(ok);
            if (tid == 0) p.flagW[0] = allok;
        }
    }

    if (phase < 0) cg::this_grid().sync();

    // ================= phase B: chunk_out (4 chunks per block) ================
    if (phase < 0 || phase == 2) {
        float* qa   = smem;             // 1024
        float* knb  = smem + 1024;
        float* zp   = smem + 2048;
        float* sW   = smem + 3072;
        float* vnT  = smem + 4096;      // [d][j], rows 36 (1152 f)
        float* lkvs = smem + 5248;      // 1024
        float* lgS  = smem + 6272;      // 32
        float* lsimS= smem + 6304;
        float* lwgt = smem + 6336;

        const int bh = bid & 15, h = bh & 7, b = bh >> 3;
        const int l = tid >> 3, e4 = (tid & 7) * 4;
        const int flag = p.flagW[0];

        for (int i = 0; i < 4; ++i) {
            const int c = (bid >> 4) * 4 + i;   // 0..63
            __syncthreads();   // protect smem reuse across iterations/phases

            const size_t base4 = ((size_t)bh * Ls + (size_t)c * T) * 8 + tid;
            const float4 qv4 = ((const float4*)p.qh)[base4];
            const float4 kn4 = ((const float4*)p.kh)[base4];
            const float4 vn4 = ((const float4*)p.vh)[base4];
            const float4 z4  = ((const float4*)p.ZcT)[((size_t)bh * NCH + c) * 256 + tid];
            const float4 la4 = *(const float4*)&p.aW[h * 32 + e4];
            const float4 lb4 = *(const float4*)&p.bW[h * 32 + e4];
            if (tid < 32) {
                lgS[tid] = p.gG[bh * Ls + c * T + tid];
                lsimS[tid] = p.simG[bh * Ls + c * T + tid];
            }
            if (!flag) {
                *(float4*)&lkvs[tid * 4] = *(const float4*)&p.kvs[h * 1024 + tid * 4];
            }
            {
                float4 q = qv4, k = kn4;
                if (flag) {
                    q.x *= la4.x; q.y *= la4.y; q.z *= la4.z; q.w *= la4.w;
                    k.x *= lb4.x; k.y *= lb4.y; k.z *= lb4.z; k.w *= lb4.w;
                }
                *(float4*)&qa[l * 32 + e4] = q;
                *(float4*)&knb[l * 32 + e4] = k;
                *(float4*)&zp[tid * 4] = z4;
                vnT[(e4 + 0) * 36 + l] = vn4.x;
                vnT[(e4 + 1) * 36 + l] = vn4.y;
                vnT[(e4 + 2) * 36 + l] = vn4.z;
                vnT[(e4 + 3) * 36 + l] = vn4.w;
            }
            __syncthreads();

            if (tid < 32) {
                float m = lsimS[tid], s = 1.f, g = lgS[tid];
#pragma unroll
                for (int off = 1; off < 32; off <<= 1) {
                    const float mo = __shfl_up(m, off);
                    const float so = __shfl_up(s, off);
                    const float go = __shfl_up(g, off);
                    if (tid >= off) {
                        const float mn = fmaxf(m, mo);
                        s = s * __expf(m - mn) + so * __expf(mo - mn);
                        m = mn;
                        g += go;
                    }
                }
                const float mp = p.mT[bh * NCH + c];
                const float sp = p.sT[bh * NCH + c];
                const float gp = p.gTt[bh * NCH + c];
                const float mn = fmaxf(mp, m);
                s = sp * __expf(mp - mn) + s * __expf(m - mn);
                m = mn;
                g += gp;
                const float sw = __expf(lsimS[tid] - m) / (s + EPSV);
                const float sig = 1.f / (1.f + __expf(-sw));
                lwgt[tid] = (1.f + sw * sig) / (g + EPSV);
            }

            float4 y4 = make_float4(0.f, 0.f, 0.f, 0.f);
            if (flag) {
                float qrow[32];
#pragma unroll
                for (int d4 = 0; d4 < 8; ++d4)
                    *(float4*)&qrow[d4 * 4] = *(const float4*)&qa[l * 32 + d4 * 4];
                float4 s4 = make_float4(0.f, 0.f, 0.f, 0.f);
#pragma unroll 8
                for (int d = 0; d < 32; ++d) {
                    const float qd = qrow[d];
                    const float4 v4 = *(const float4*)&vnT[d * 36 + e4];
                    const float4 p4 = *(const float4*)&zp[d * 32 + e4];
                    s4.x = fmaf(qd, v4.x, s4.x);
                    s4.y = fmaf(qd, v4.y, s4.y);
                    s4.z = fmaf(qd, v4.z, s4.z);
                    s4.w = fmaf(qd, v4.w, s4.w);
                    y4.x = fmaf(qd, p4.x, y4.x);
                    y4.y = fmaf(qd, p4.y, y4.y);
                    y4.z = fmaf(qd, p4.z, y4.z);
                    y4.w = fmaf(qd, p4.w, y4.w);
                }
                y4.x *= lb4.x; y4.y *= lb4.y; y4.z *= lb4.z; y4.w *= lb4.w;
                const float4 lg4 = *(const float4*)&lgS[e4];
                float4 sm;
                sm.x = (e4 + 0 <= l) ? lg4.x * s4.x : 0.f;
                sm.y = (e4 + 1 <= l) ? lg4.y * s4.y : 0.f;
                sm.z = (e4 + 2 <= l) ? lg4.z * s4.z : 0.f;
                sm.w = (e4 + 3 <= l) ? lg4.w * s4.w : 0.f;
                *(float4*)&sW[l * 32 + e4] = sm;
                __syncthreads();
                float srow[32];
#pragma unroll
                for (int j4 = 0; j4 < 8; ++j4)
                    *(float4*)&srow[j4 * 4] = *(const float4*)&sW[l * 32 + j4 * 4];
#pragma unroll 8
                for (int j = 0; j < 32; ++j) {
                    const float sj = srow[j];
                    const float4 k4 = *(const float4*)&knb[j * 32 + e4];
                    y4.x = fmaf(sj, k4.x, y4.x);
                    y4.y = fmaf(sj, k4.y, y4.y);
                    y4.z = fmaf(sj, k4.z, y4.z);
                    y4.w = fmaf(sj, k4.w, y4.w);
                }
            } else {
                __syncthreads();
                float* yp = &y4.x;
#pragma unroll
                for (int ii = 0; ii < 4; ++ii) {
                    const int e = e4 + ii;
                    float qe[32];
#pragma unroll
                    for (int d = 0; d < 32; ++d)
                        qe[d] = qa[l * 32 + d] * lkvs[d * 32 + e];
                    float y = 0.f;
#pragma unroll
                    for (int d = 0; d < 32; ++d)
                        y = fmaf(qe[d], zp[d * 32 + e], y);
                    for (int j = 0; j < 32; ++j) {
                        float s = 0.f;
#pragma unroll
                        for (int d = 0; d < 32; ++d)
                            s = fmaf(qe[d], vnT[d * 36 + j], s);
                        if (j <= l) y = fmaf(lgS[j] * s, knb[j * 32 + e], y);
                    }
                    yp[ii] = y;
                }
            }
            const float w = lwgt[l];
            ushort4 hi4, lo4;
            split_bf16(y4.x * w, hi4.x, lo4.x);
            split_bf16(y4.y * w, hi4.y, lo4.y);
            split_bf16(y4.z * w, hi4.z, lo4.z);
            split_bf16(y4.w * w, hi4.w, lo4.w);
            const size_t oidx = ((size_t)(b * Ls + c * T + l)) * 256 + h * 32 + e4;
            *(ushort4*)&p.chi[oidx] = hi4;
            *(ushort4*)&p.clo[oidx] = lo4;
        }
    }

    if (phase < 0) cg::this_grid().sync();

    // ================= phase C: out-proj GEMM =================================
    if (phase < 0 || phase == 3) {
        constexpr int LDK = 40;
        u16* As_hi = (u16*)smem;        // 2560 each
        u16* As_lo = As_hi + 2560;
        u16* Ws_hi = As_lo + 2560;
        u16* Ws_lo = Ws_hi + 2560;

        const int mt = bid & 63, nt = bid >> 6;
        const int m0 = mt * 64, ncol0 = nt * 64;
        const int srow = tid >> 2, sk = (tid & 3) * 8;

        f32x4 acc[4] = {};

        for (int k0 = 0; k0 < 256; k0 += 32) {
            const uint4 ah = *(const uint4*)&p.chi[(size_t)(m0 + srow) * 256 + k0 + sk];
            const uint4 al = *(const uint4*)&p.clo[(size_t)(m0 + srow) * 256 + k0 + sk];
            const float4 w0 = *(const float4*)&p.wo[(size_t)(ncol0 + srow) * 256 + k0 + sk];
            const float4 w1 = *(const float4*)&p.wo[(size_t)(ncol0 + srow) * 256 + k0 + sk + 4];
            __syncthreads();
            uint4 whi, wlo;
            split8(w0, w1, whi, wlo);
            *(uint4*)&As_hi[srow * LDK + sk] = ah;
            *(uint4*)&As_lo[srow * LDK + sk] = al;
            *(uint4*)&Ws_hi[srow * LDK + sk] = whi;
            *(uint4*)&Ws_lo[srow * LDK + sk] = wlo;
            __syncthreads();

            const frag fah = *(const frag*)&As_hi[(wave * 16 + l15) * LDK + quad * 8];
            const frag fal = *(const frag*)&As_lo[(wave * 16 + l15) * LDK + quad * 8];
#pragma unroll
            for (int cf = 0; cf < 4; ++cf) {
                const frag fbh = *(const frag*)&Ws_hi[(cf * 16 + l15) * LDK + quad * 8];
                const frag fbl = *(const frag*)&Ws_lo[(cf * 16 + l15) * LDK + quad * 8];
                acc[cf] = __builtin_amdgcn_mfma_f32_16x16x32_bf16(fah, fbh, acc[cf], 0, 0, 0);
                acc[cf] = __builtin_amdgcn_mfma_f32_16x16x32_bf16(fah, fbl, acc[cf], 0, 0, 0);
                acc[cf] = __builtin_amdgcn_mfma_f32_16x16x32_bf16(fal, fbh, acc[cf], 0, 0, 0);
            }
        }

#pragma unroll
        for (int cf = 0; cf < 4; ++cf) {
            const int o = ncol0 + cf * 16 + l15;
            const float bias = p.bo[o];
#pragma unroll
            for (int r = 0; r < 4; ++r) {
                const int rm = m0 + wave * 16 + quad * 4 + r;
                p.out[(size_t)rm * 256 + o] = acc[cf][r] + bias;
            }
        }
    }
}

extern "C" void kernel_launch(void* const* d_in, const int* in_sizes, int n_in,
                              void* d_out, int out_size, void* d_ws, size_t ws_size,
                              hipStream_t stream) {
    Params p;
    p.x    = (const float*)d_in[0];
    p.wq   = (const float*)d_in[1];
    p.bq   = (const float*)d_in[2];
    p.wk   = (const float*)d_in[3];
    p.bk   = (const float*)d_in[4];
    p.wv   = (const float*)d_in[5];
    p.bv   = (const float*)d_in[6];
    p.wo   = (const float*)d_in[7];
    p.bo   = (const float*)d_in[8];
    p.wg_w = (const float*)d_in[9];
    p.wg_b = (const float*)d_in[10];
    p.kvs  = (const float*)d_in[11];
    p.qks  = (const float*)d_in[12];
    p.out  = (float*)d_out;

    u16* chi = (u16*)d_ws;                 // 1048576 u16
    u16* clo = chi + 1048576;              // 1048576 u16
    float* qh   = (float*)(clo + 1048576); // fp32 region
    p.chi = chi; p.clo = clo;
    p.qh  = qh;
    p.kh  = qh + 1048576;
    p.vh  = p.kh + 1048576;
    p.ZcT = p.vh + 1048576;                // 1048576
    p.simG= p.ZcT + 1048576;               // 32768
    p.gG  = p.simG + 32768;                // 32768
    p.mT  = p.gG + 32768;                  // 1024
    p.sT  = p.mT + 1024;
    p.gTt = p.sT + 1024;
    p.aW  = p.gTt + 1024;                  // 256
    p.bW  = p.aW + 256;                    // 256
    p.flagW = (int*)(p.bW + 256);

    int dev = 0, coop = 0;
    hipGetDevice(&dev);
    hipDeviceGetAttribute(&coop, hipDeviceAttributeCooperativeLaunch, dev);

    hipError_t err = hipErrorUnknown;
    if (coop) {
        int ph = -1;
        void* args[] = { &p, &ph };
        err = hipLaunchCooperativeKernel((const void*)mega_kernel,
                                         dim3(256), dim3(256), args, 0, stream);
    }
    if (err != hipSuccess) {
        // deterministic fallback: same kernel, one phase per normal launch
        for (int ph = 0; ph < 4; ++ph)
            mega_kernel<<<256, 256, 0, stream>>>(p, ph);
    }
}

// Round 9
// 154.345 us; speedup vs baseline: 1.6088x; 1.6088x over previous
//
#include <hip/hip_runtime.h>
#include <math.h>

#define EPSV 1e-5f

static constexpr int Ls = 2048, Hh = 8;
static constexpr int NCH = 64, T = 32;   // 64 chunks of 32 along L

typedef unsigned short u16;
using frag  = __attribute__((ext_vector_type(8))) short;   // 8 x bf16 (4 VGPRs)
using f32x4 = __attribute__((ext_vector_type(4))) float;

__device__ __forceinline__ void split_bf16(float v, u16& hi, u16& lo) {
    const unsigned u = __float_as_uint(v);
    hi = (u16)(u >> 16);
    const float hf = __uint_as_float((unsigned)hi << 16);
    lo = (u16)(__float_as_uint(v - hf) >> 16);
}

__device__ __forceinline__ unsigned pk2(u16 a, u16 b) {
    return (unsigned)a | ((unsigned)b << 16);
}

__device__ __forceinline__ void split8(const float4& a, const float4& b,
                                       uint4& hi, uint4& lo) {
    u16 h[8], l[8];
    const float f[8] = {a.x, a.y, a.z, a.w, b.x, b.y, b.z, b.w};
#pragma unroll
    for (int i = 0; i < 8; ++i) split_bf16(f[i], h[i], l[i]);
    hi = make_uint4(pk2(h[0], h[1]), pk2(h[2], h[3]), pk2(h[4], h[5]), pk2(h[6], h[7]));
    lo = make_uint4(pk2(l[0], l[1]), pk2(l[2], l[3]), pk2(l[4], l[5]), pk2(l[6], l[7]));
}

// =====================================================================
// K1: qkv split-bf16 MFMA GEMM (register-prefetched) + chunk_sum epilogue
// grid (64 row-tiles, 4 head-pairs) x 256. Block 0 also does rank-1 setup.
// =====================================================================
__global__ __launch_bounds__(256) void qkv_fused(
    const float* __restrict__ x,
    const float* __restrict__ wq, const float* __restrict__ wk, const float* __restrict__ wv,
    const float* __restrict__ bq, const float* __restrict__ bk, const float* __restrict__ bv,
    const float* __restrict__ wg_w, const float* __restrict__ wg_b,
    const float* __restrict__ kvs, const float* __restrict__ qks,
    float* __restrict__ qh, float* __restrict__ kh, float* __restrict__ vh,
    float* __restrict__ simG, float* __restrict__ gG,
    float* __restrict__ ZcT, float* __restrict__ mT, float* __restrict__ sT,
    float* __restrict__ gTt,
    float* __restrict__ aW, float* __restrict__ bW, int* __restrict__ flagW)
{
    constexpr int LDK = 40;     // u16 per staged row
    constexpr int LDT = 68;     // f32 per tile row (272 B, float4-aligned)
    __shared__ __align__(16) float smemf[3 * 64 * LDT];   // staging aliases tiles
    __shared__ __align__(16) float wkT[2 * 1152];         // [h][e*36+d]
    __shared__ float lsim[128], lg2[128];

    u16* As_hi = (u16*)smemf;          // 2560 u16
    u16* As_lo = As_hi + 2560;
    u16* Wst   = As_lo + 2560;         // weight w: hi at w*5120, lo +2560
    float* Qt = smemf;
    float* Kt = Qt + 64 * LDT;
    float* Vt = Kt + 64 * LDT;

    const int tid = threadIdx.x;
    const int mt = blockIdx.x, nt = blockIdx.y;
    const int m0 = mt * 64, ncol0 = nt * 64;
    const int bidx = m0 >> 11, lg = m0 & (Ls - 1);
    const int wave = tid >> 6, lane = tid & 63;
    const int l15 = lane & 15, quad = lane >> 4;
    const int srow = tid >> 2, sk = (tid & 3) * 8;

    for (int i = tid; i < 2048; i += 256) {
        const int h = i >> 10, de = i & 1023;
        const int d = de >> 5, e = de & 31;
        wkT[h * 1152 + e * 36 + d] = wg_w[de] * kvs[(nt * 2 + h) * 1024 + de];
    }

    const float* Wsrc[3] = {wq, wk, wv};
    f32x4 acc[3][4] = {};

    // prefetch iter 0
    float4 a0 = *(const float4*)&x[(size_t)(m0 + srow) * 256 + sk];
    float4 a1 = *(const float4*)&x[(size_t)(m0 + srow) * 256 + sk + 4];
    float4 w0[3], w1[3];
#pragma unroll
    for (int w = 0; w < 3; ++w) {
        w0[w] = *(const float4*)&Wsrc[w][(size_t)(ncol0 + srow) * 256 + sk];
        w1[w] = *(const float4*)&Wsrc[w][(size_t)(ncol0 + srow) * 256 + sk + 4];
    }

    for (int it = 0; it < 8; ++it) {
        __syncthreads();
        {
            uint4 hi, lo;
            split8(a0, a1, hi, lo);
            *(uint4*)&As_hi[srow * LDK + sk] = hi;
            *(uint4*)&As_lo[srow * LDK + sk] = lo;
#pragma unroll
            for (int w = 0; w < 3; ++w) {
                split8(w0[w], w1[w], hi, lo);
                *(uint4*)&Wst[w * 5120 + srow * LDK + sk] = hi;
                *(uint4*)&Wst[w * 5120 + 2560 + srow * LDK + sk] = lo;
            }
        }
        __syncthreads();

        if (it < 7) {   // issue next-iter loads; they fly during MFMA below
            const int k0 = (it + 1) * 32;
            a0 = *(const float4*)&x[(size_t)(m0 + srow) * 256 + k0 + sk];
            a1 = *(const float4*)&x[(size_t)(m0 + srow) * 256 + k0 + sk + 4];
#pragma unroll
            for (int w = 0; w < 3; ++w) {
                w0[w] = *(const float4*)&Wsrc[w][(size_t)(ncol0 + srow) * 256 + k0 + sk];
                w1[w] = *(const float4*)&Wsrc[w][(size_t)(ncol0 + srow) * 256 + k0 + sk + 4];
            }
        }

        frag ah[4], al[4];
#pragma unroll
        for (int tm = 0; tm < 4; ++tm) {
            const int r = tm * 16 + l15;
            ah[tm] = *(const frag*)&As_hi[r * LDK + quad * 8];
            al[tm] = *(const frag*)&As_lo[r * LDK + quad * 8];
        }
#pragma unroll
        for (int w = 0; w < 3; ++w) {
            const u16* bp = &Wst[w * 5120 + (wave * 16 + l15) * LDK + quad * 8];
            const frag bh = *(const frag*)bp;
            const frag bl = *(const frag*)(bp + 2560);
#pragma unroll
            for (int tm = 0; tm < 4; ++tm) {
                acc[w][tm] = __builtin_amdgcn_mfma_f32_16x16x32_bf16(ah[tm], bh, acc[w][tm], 0, 0, 0);
                acc[w][tm] = __builtin_amdgcn_mfma_f32_16x16x32_bf16(ah[tm], bl, acc[w][tm], 0, 0, 0);
                acc[w][tm] = __builtin_amdgcn_mfma_f32_16x16x32_bf16(al[tm], bh, acc[w][tm], 0, 0, 0);
            }
        }
    }
    __syncthreads();   // staging dead; write tiles (aliased region)

    {
        float* tiles[3] = {Qt, Kt, Vt};
        const float* biases[3] = {bq, bk, bv};
#pragma unroll
        for (int w = 0; w < 3; ++w) {
            const int col = wave * 16 + l15;
            const float bias = biases[w][ncol0 + col];
#pragma unroll
            for (int tm = 0; tm < 4; ++tm)
#pragma unroll
                for (int r = 0; r < 4; ++r) {
                    const int m = tm * 16 + quad * 4 + r;
                    tiles[w][m * LDT + col] = acc[w][tm][r] + bias;
                }
        }
    }
    __syncthreads();

    // ---- normalize k,v in place; sim ----
    if (tid < 128) {
        const int h = tid >> 6, l = tid & 63;
        const int rb = l * LDT + h * 32;
        float4 kr[8], vr[8];
        float ksum = 0.f, vsum = 0.f, qk = 0.f;
#pragma unroll
        for (int e4 = 0; e4 < 8; ++e4) {
            kr[e4] = *(const float4*)&Kt[rb + e4 * 4];
            vr[e4] = *(const float4*)&Vt[rb + e4 * 4];
            const float4 q4 = *(const float4*)&Qt[rb + e4 * 4];
            ksum += kr[e4].x * kr[e4].x + kr[e4].y * kr[e4].y + kr[e4].z * kr[e4].z + kr[e4].w * kr[e4].w;
            vsum += vr[e4].x * vr[e4].x + vr[e4].y * vr[e4].y + vr[e4].z * vr[e4].z + vr[e4].w * vr[e4].w;
            qk   += q4.x * kr[e4].x + q4.y * kr[e4].y + q4.z * kr[e4].z + q4.w * kr[e4].w;
        }
        const float kscale = 1.f / fmaxf(sqrtf(ksum), 1e-12f);
        const float vscale = 1.f / fmaxf(sqrtf(vsum), 1e-12f);
#pragma unroll
        for (int e4 = 0; e4 < 8; ++e4) {
            float4 k4 = kr[e4], v4 = vr[e4];
            k4.x *= kscale; k4.y *= kscale; k4.z *= kscale; k4.w *= kscale;
            v4.x *= vscale; v4.y *= vscale; v4.z *= vscale; v4.w *= vscale;
            *(float4*)&Kt[rb + e4 * 4] = k4;
            *(float4*)&Vt[rb + e4 * 4] = v4;
        }
        const float sim = qk * qks[nt * 2 + h];
        lsim[h * 64 + l] = sim;
        simG[(size_t)(bidx * 8 + nt * 2 + h) * Ls + lg + l] = sim;
    }
    __syncthreads();

    // ---- copy q, kn, vn to global ----
    {
        const float* tl[3] = {Qt, Kt, Vt};
        float* gl[3] = {qh, kh, vh};
#pragma unroll
        for (int arr = 0; arr < 3; ++arr)
#pragma unroll
            for (int it = 0; it < 4; ++it) {
                const int idx = it * 1024 + tid * 4;
                const int h = idx >> 11, rem = idx & 2047;
                const int l = rem >> 5, e4 = rem & 31;
                const float4 v = *(const float4*)&tl[arr][l * LDT + h * 32 + e4];
                *(float4*)&gl[arr][(size_t)(bidx * 8 + nt * 2 + h) * 65536 +
                                   (size_t)(lg + l) * 32 + e4] = v;
            }
    }

    // ---- gate per (h,l); 2 threads per task ----
    {
        const int task = tid >> 1, half = tid & 1;
        const int h = task >> 6, l = task & 63;
        float4 vr[8];
#pragma unroll
        for (int d4 = 0; d4 < 8; ++d4)
            vr[d4] = *(const float4*)&Vt[l * LDT + h * 32 + d4 * 4];
        float u = 0.f;
        const int e0 = half * 16;
#pragma unroll 4
        for (int e = e0; e < e0 + 16; ++e) {
            float4 s4 = make_float4(0.f, 0.f, 0.f, 0.f);
#pragma unroll
            for (int d4 = 0; d4 < 8; ++d4) {
                const float4 w4 = *(const float4*)&wkT[h * 1152 + e * 36 + d4 * 4];
                s4.x = fmaf(vr[d4].x, w4.x, s4.x);
                s4.y = fmaf(vr[d4].y, w4.y, s4.y);
                s4.z = fmaf(vr[d4].z, w4.z, s4.z);
                s4.w = fmaf(vr[d4].w, w4.w, s4.w);
            }
            u = fmaf(s4.x + s4.y + s4.z + s4.w, Kt[l * LDT + h * 32 + e], u);
        }
        u += __shfl_xor(u, 1);
        if (half == 0) {
            const float r = fmaxf(u + wg_b[0], 0.f);
            const float g = r * r + EPSV;
            lg2[h * 64 + l] = g;
            gG[(size_t)(bidx * 8 + nt * 2 + h) * Ls + lg + l] = g;
        }
    }
    __syncthreads();

    // ---- chunk-Z totals ----
    {
        const int d = tid >> 3, e4m = (tid & 7) * 4;
#pragma unroll
        for (int h = 0; h < 2; ++h)
#pragma unroll
            for (int cc = 0; cc < 2; ++cc) {
                float4 z4 = make_float4(0.f, 0.f, 0.f, 0.f);
#pragma unroll 8
                for (int l = 0; l < 32; ++l) {
                    const int lr = cc * 32 + l;
                    const float gv = lg2[h * 64 + lr] * Vt[lr * LDT + h * 32 + d];
                    const float4 k4 = *(const float4*)&Kt[lr * LDT + h * 32 + e4m];
                    z4.x = fmaf(gv, k4.x, z4.x);
                    z4.y = fmaf(gv, k4.y, z4.y);
                    z4.z = fmaf(gv, k4.z, z4.z);
                    z4.w = fmaf(gv, k4.w, z4.w);
                }
                const int bhg = bidx * 8 + nt * 2 + h;
                const int cg = (lg >> 5) + cc;
                *(float4*)&ZcT[((size_t)bhg * NCH + cg) * 1024 + d * 32 + e4m] = z4;
            }
    }

    // ---- (m,s,g) raw chunk totals ----
    {
        const int h = wave >> 1, cc = wave & 1;
        if (lane < 32) {
            const int lr = cc * 32 + lane;
            float m = lsim[h * 64 + lr], s = 1.f, g = lg2[h * 64 + lr];
#pragma unroll
            for (int off = 16; off; off >>= 1) {
                const float mo = __shfl_xor(m, off);
                const float so = __shfl_xor(s, off);
                const float mn = fmaxf(m, mo);
                s = s * __expf(m - mn) + so * __expf(mo - mn);
                m = mn;
                g += __shfl_xor(g, off);
            }
            if (lane == 0) {
                const int bhg = bidx * 8 + nt * 2 + h;
                const int cg = (lg >> 5) + cc;
                mT[bhg * NCH + cg] = m;
                sT[bhg * NCH + cg] = s;
                gTt[bhg * NCH + cg] = g;
            }
        }
    }

    // ---- rank-1 kvs setup (block 0 only) ----
    if (mt == 0 && nt == 0) {
        const int h = tid >> 5, e = tid & 31;
        const float* K = kvs + h * 1024;
        const float k00 = K[0];
        int ok = (k00 != 0.0f);
        for (int d = 0; d < 32; ++d) {
            const float lhs = K[d * 32 + e] * k00;
            const float rhs = K[d * 32] * K[e];
            const float diff = fabsf(lhs - rhs);
            if (diff > 1e-6f * fmaxf(fmaxf(fabsf(lhs), fabsf(rhs)), 1e-20f)) ok = 0;
        }
        aW[h * 32 + e] = K[e * 32];
        bW[h * 32 + e] = (k00 != 0.0f) ? K[e] / k00 : 0.f;
        const int allok = __syncthreads_and(ok);
        if (tid == 0) flagW[0] = allok;
    }
}

// =====================================================================
// K2: chunk_out with inline Z-prefix + (m,s,g) wave64 scan
// grid (NCH=64, 16 bh) x 256 threads
// =====================================================================
__global__ __launch_bounds__(256) void chunk_out_kernel(
    const float* __restrict__ qh, const float* __restrict__ knG, const float* __restrict__ vnG,
    const float* __restrict__ simG, const float* __restrict__ gG,
    const float* __restrict__ kvs,
    const float* __restrict__ ZcT, const float* __restrict__ mT,
    const float* __restrict__ sT, const float* __restrict__ gTt,
    const float* __restrict__ aW, const float* __restrict__ bW,
    const int* __restrict__ flagW,
    u16* __restrict__ chi, u16* __restrict__ clo)
{
    __shared__ __align__(16) float qa[1024], knb[1024], zp[1024], sW[1024];
    __shared__ __align__(16) float vnT[32 * 36];   // [d][j]
    __shared__ float lkvs[1024];                    // fallback only
    __shared__ float lgS[32], lsimS[32], lwgt[32];
    const int tid = threadIdx.x;
    const int c = blockIdx.x, bh = blockIdx.y, h = bh & 7, b = bh >> 3;
    const int l = tid >> 3, e4 = (tid & 7) * 4;
    const size_t base4 = ((size_t)bh * Ls + (size_t)c * T) * 8 + tid;   // float4 idx
    const int flag = flagW[0];

    // ---- inline Z-prefix: sum chunk-total tiles 0..c-1 (8-batched, L2-resident)
    {
        const float4* Zt = (const float4*)ZcT + (size_t)bh * NCH * 256 + tid;
        float4 zacc = make_float4(0.f, 0.f, 0.f, 0.f);
        int cb = 0;
        for (; cb + 8 <= c; cb += 8) {
            float4 v[8];
#pragma unroll
            for (int i = 0; i < 8; ++i) v[i] = Zt[(size_t)(cb + i) * 256];
#pragma unroll
            for (int i = 0; i < 8; ++i) {
                zacc.x += v[i].x; zacc.y += v[i].y; zacc.z += v[i].z; zacc.w += v[i].w;
            }
        }
        for (; cb < c; ++cb) {
            const float4 v = Zt[(size_t)cb * 256];
            zacc.x += v.x; zacc.y += v.y; zacc.z += v.z; zacc.w += v.w;
        }
        *(float4*)&zp[tid * 4] = zacc;
    }

    const float4 qv4 = ((const float4*)qh)[base4];
    const float4 kn4 = ((const float4*)knG)[base4];
    const float4 vn4 = ((const float4*)vnG)[base4];
    const float4 la4 = *(const float4*)&aW[h * 32 + e4];
    const float4 lb4 = *(const float4*)&bW[h * 32 + e4];
    if (tid < 32) {
        lgS[tid] = gG[bh * Ls + c * T + tid];
        lsimS[tid] = simG[bh * Ls + c * T + tid];
    }
    if (!flag) {
        *(float4*)&lkvs[tid * 4] = *(const float4*)&kvs[h * 1024 + tid * 4];
    }
    {
        float4 q = qv4, k = kn4;
        if (flag) {
            q.x *= la4.x; q.y *= la4.y; q.z *= la4.z; q.w *= la4.w;
            k.x *= lb4.x; k.y *= lb4.y; k.z *= lb4.z; k.w *= lb4.w;
        }
        *(float4*)&qa[l * 32 + e4] = q;
        *(float4*)&knb[l * 32 + e4] = k;
        vnT[(e4 + 0) * 36 + l] = vn4.x;
        vnT[(e4 + 1) * 36 + l] = vn4.y;
        vnT[(e4 + 2) * 36 + l] = vn4.z;
        vnT[(e4 + 3) * 36 + l] = vn4.w;
    }
    __syncthreads();

    if (tid < 64) {
        // chunk-level (m,s,g) prefix: inclusive wave64 scan of raw totals, pick c-1
        float mC = mT[bh * NCH + tid], sC = sT[bh * NCH + tid], gC = gTt[bh * NCH + tid];
#pragma unroll
        for (int off = 1; off < 64; off <<= 1) {
            const float mo = __shfl_up(mC, off);
            const float so = __shfl_up(sC, off);
            const float go = __shfl_up(gC, off);
            if (tid >= off) {
                const float mn = fmaxf(mC, mo);
                sC = sC * __expf(mC - mn) + so * __expf(mo - mn);
                mC = mn;
                gC += go;
            }
        }
        const float mp = (c > 0) ? __shfl(mC, c - 1) : -1e30f;
        const float sp = (c > 0) ? __shfl(sC, c - 1) : 0.f;
        const float gp = (c > 0) ? __shfl(gC, c - 1) : 0.f;

        if (tid < 32) {
            float m = lsimS[tid], s = 1.f, g = lgS[tid];
#pragma unroll
            for (int off = 1; off < 32; off <<= 1) {
                const float mo = __shfl_up(m, off);
                const float so = __shfl_up(s, off);
                const float go = __shfl_up(g, off);
                if (tid >= off) {
                    const float mn = fmaxf(m, mo);
                    s = s * __expf(m - mn) + so * __expf(mo - mn);
                    m = mn;
                    g += go;
                }
            }
            const float mn = fmaxf(mp, m);
            s = sp * __expf(mp - mn) + s * __expf(m - mn);
            m = mn;
            g += gp;
            const float sw = __expf(lsimS[tid] - m) / (s + EPSV);
            const float sig = 1.f / (1.f + __expf(-sw));
            lwgt[tid] = (1.f + sw * sig) / (g + EPSV);
        }
    }

    float4 y4 = make_float4(0.f, 0.f, 0.f, 0.f);
    if (flag) {
        float qrow[32];
#pragma unroll
        for (int d4 = 0; d4 < 8; ++d4)
            *(float4*)&qrow[d4 * 4] = *(const float4*)&qa[l * 32 + d4 * 4];
        float4 s4 = make_float4(0.f, 0.f, 0.f, 0.f);
#pragma unroll 8
        for (int d = 0; d < 32; ++d) {
            const float qd = qrow[d];
            const float4 v4 = *(const float4*)&vnT[d * 36 + e4];
            const float4 p4 = *(const float4*)&zp[d * 32 + e4];
            s4.x = fmaf(qd, v4.x, s4.x);
            s4.y = fmaf(qd, v4.y, s4.y);
            s4.z = fmaf(qd, v4.z, s4.z);
            s4.w = fmaf(qd, v4.w, s4.w);
            y4.x = fmaf(qd, p4.x, y4.x);
            y4.y = fmaf(qd, p4.y, y4.y);
            y4.z = fmaf(qd, p4.z, y4.z);
            y4.w = fmaf(qd, p4.w, y4.w);
        }
        y4.x *= lb4.x; y4.y *= lb4.y; y4.z *= lb4.z; y4.w *= lb4.w;
        const float4 lg4 = *(const float4*)&lgS[e4];
        float4 sm;
        sm.x = (e4 + 0 <= l) ? lg4.x * s4.x : 0.f;
        sm.y = (e4 + 1 <= l) ? lg4.y * s4.y : 0.f;
        sm.z = (e4 + 2 <= l) ? lg4.z * s4.z : 0.f;
        sm.w = (e4 + 3 <= l) ? lg4.w * s4.w : 0.f;
        *(float4*)&sW[l * 32 + e4] = sm;
        __syncthreads();
        float srow[32];
#pragma unroll
        for (int j4 = 0; j4 < 8; ++j4)
            *(float4*)&srow[j4 * 4] = *(const float4*)&sW[l * 32 + j4 * 4];
#pragma unroll 8
        for (int j = 0; j < 32; ++j) {
            const float sj = srow[j];
            const float4 k4 = *(const float4*)&knb[j * 32 + e4];
            y4.x = fmaf(sj, k4.x, y4.x);
            y4.y = fmaf(sj, k4.y, y4.y);
            y4.z = fmaf(sj, k4.z, y4.z);
            y4.w = fmaf(sj, k4.w, y4.w);
        }
    } else {
        __syncthreads();
        float* yp = &y4.x;
#pragma unroll
        for (int ii = 0; ii < 4; ++ii) {
            const int e = e4 + ii;
            float qe[32];
#pragma unroll
            for (int d = 0; d < 32; ++d)
                qe[d] = qa[l * 32 + d] * lkvs[d * 32 + e];
            float y = 0.f;
#pragma unroll
            for (int d = 0; d < 32; ++d)
                y = fmaf(qe[d], zp[d * 32 + e], y);
            for (int j = 0; j < 32; ++j) {
                float s = 0.f;
#pragma unroll
                for (int d = 0; d < 32; ++d)
                    s = fmaf(qe[d], vnT[d * 36 + j], s);
                if (j <= l) y = fmaf(lgS[j] * s, knb[j * 32 + e], y);
            }
            yp[ii] = y;
        }
    }
    const float w = lwgt[l];
    ushort4 hi4, lo4;
    split_bf16(y4.x * w, hi4.x, lo4.x);
    split_bf16(y4.y * w, hi4.y, lo4.y);
    split_bf16(y4.z * w, hi4.z, lo4.z);
    split_bf16(y4.w * w, hi4.w, lo4.w);
    const size_t oidx = ((size_t)(b * Ls + c * T + l)) * 256 + h * 32 + e4;
    *(ushort4*)&chi[oidx] = hi4;
    *(ushort4*)&clo[oidx] = lo4;
}

// =====================================================================
// K3: out-proj GEMM, register-prefetched; W split on the fly
// grid (64, 4) x 256
// =====================================================================
__global__ __launch_bounds__(256) void out_gemm(
    const u16* __restrict__ Ahi, const u16* __restrict__ Alo,
    const float* __restrict__ wo, const float* __restrict__ bo,
    float* __restrict__ out)
{
    constexpr int LDK = 40;
    __shared__ __align__(16) u16 As_hi[64 * LDK];
    __shared__ __align__(16) u16 As_lo[64 * LDK];
    __shared__ __align__(16) u16 Ws_hi[64 * LDK];
    __shared__ __align__(16) u16 Ws_lo[64 * LDK];

    const int tid = threadIdx.x;
    const int mt = blockIdx.x, nt = blockIdx.y;
    const int m0 = mt * 64, ncol0 = nt * 64;
    const int wave = tid >> 6, lane = tid & 63;
    const int l15 = lane & 15, quad = lane >> 4;
    const int srow = tid >> 2, sk = (tid & 3) * 8;

    f32x4 acc[4] = {};

    uint4 ah = *(const uint4*)&Ahi[(size_t)(m0 + srow) * 256 + sk];
    uint4 al = *(const uint4*)&Alo[(size_t)(m0 + srow) * 256 + sk];
    float4 w0 = *(const float4*)&wo[(size_t)(ncol0 + srow) * 256 + sk];
    float4 w1 = *(const float4*)&wo[(size_t)(ncol0 + srow) * 256 + sk + 4];

    for (int it = 0; it < 8; ++it) {
        __syncthreads();
        {
            uint4 whi, wlo;
            split8(w0, w1, whi, wlo);
            *(uint4*)&As_hi[srow * LDK + sk] = ah;
            *(uint4*)&As_lo[srow * LDK + sk] = al;
            *(uint4*)&Ws_hi[srow * LDK + sk] = whi;
            *(uint4*)&Ws_lo[srow * LDK + sk] = wlo;
        }
        __syncthreads();

        if (it < 7) {
            const int k0 = (it + 1) * 32;
            ah = *(const uint4*)&Ahi[(size_t)(m0 + srow) * 256 + k0 + sk];
            al = *(const uint4*)&Alo[(size_t)(m0 + srow) * 256 + k0 + sk];
            w0 = *(const float4*)&wo[(size_t)(ncol0 + srow) * 256 + k0 + sk];
            w1 = *(const float4*)&wo[(size_t)(ncol0 + srow) * 256 + k0 + sk + 4];
        }

        const frag fah = *(const frag*)&As_hi[(wave * 16 + l15) * LDK + quad * 8];
        const frag fal = *(const frag*)&As_lo[(wave * 16 + l15) * LDK + quad * 8];
#pragma unroll
        for (int cf = 0; cf < 4; ++cf) {
            const frag fbh = *(const frag*)&Ws_hi[(cf * 16 + l15) * LDK + quad * 8];
            const frag fbl = *(const frag*)&Ws_lo[(cf * 16 + l15) * LDK + quad * 8];
            acc[cf] = __builtin_amdgcn_mfma_f32_16x16x32_bf16(fah, fbh, acc[cf], 0, 0, 0);
            acc[cf] = __builtin_amdgcn_mfma_f32_16x16x32_bf16(fah, fbl, acc[cf], 0, 0, 0);
            acc[cf] = __builtin_amdgcn_mfma_f32_16x16x32_bf16(fal, fbh, acc[cf], 0, 0, 0);
        }
    }

#pragma unroll
    for (int cf = 0; cf < 4; ++cf) {
        const int o = ncol0 + cf * 16 + l15;
        const float bias = bo[o];
#pragma unroll
        for (int r = 0; r < 4; ++r) {
            const int rm = m0 + wave * 16 + quad * 4 + r;
            out[(size_t)rm * 256 + o] = acc[cf][r] + bias;
        }
    }
}

extern "C" void kernel_launch(void* const* d_in, const int* in_sizes, int n_in,
                              void* d_out, int out_size, void* d_ws, size_t ws_size,
                              hipStream_t stream) {
    const float* x    = (const float*)d_in[0];
    const float* wq_w = (const float*)d_in[1];
    const float* wq_b = (const float*)d_in[2];
    const float* wk_w = (const float*)d_in[3];
    const float* wk_b = (const float*)d_in[4];
    const float* wv_w = (const float*)d_in[5];
    const float* wv_b = (const float*)d_in[6];
    const float* wo_w = (const float*)d_in[7];
    const float* wo_b = (const float*)d_in[8];
    const float* wg_w = (const float*)d_in[9];
    const float* wg_b = (const float*)d_in[10];
    const float* kvs  = (const float*)d_in[11];
    const float* qks  = (const float*)d_in[12];
    float* out = (float*)d_out;

    u16* chi = (u16*)d_ws;                 // 1048576 u16
    u16* clo = chi + 1048576;              // 1048576 u16
    float* qh   = (float*)(clo + 1048576); // fp32 region
    float* kh   = qh + 1048576;
    float* vh   = kh + 1048576;
    float* ZcT  = vh + 1048576;            // 1048576
    float* simG = ZcT + 1048576;           // 32768
    float* gG   = simG + 32768;            // 32768
    float* mT   = gG + 32768;              // 1024
    float* sT   = mT + 1024;
    float* gTt  = sT + 1024;
    float* aW   = gTt + 1024;              // 256
    float* bW   = aW + 256;                // 256
    int* flagW  = (int*)(bW + 256);

    qkv_fused<<<dim3(64, 4), 256, 0, stream>>>(
        x, wq_w, wk_w, wv_w, wq_b, wk_b, wv_b, wg_w, wg_b, kvs, qks,
        qh, kh, vh, simG, gG, ZcT, mT, sT, gTt, aW, bW, flagW);
    chunk_out_kernel<<<dim3(NCH, 16), 256, 0, stream>>>(
        qh, kh, vh, simG, gG, kvs, ZcT, mT, sT, gTt, aW, bW, flagW, chi, clo);
    out_gemm<<<dim3(64, 4), 256, 0, stream>>>(
        chi, clo, wo_w, wo_b, out);
}

// Round 10
// 152.804 us; speedup vs baseline: 1.6250x; 1.0101x over previous
//
#include <hip/hip_runtime.h>
#include <math.h>

#define EPSV 1e-5f

static constexpr int Ls = 2048, Hh = 8;
static constexpr int NCH = 64, T = 32;   // 64 chunks of 32 along L

typedef unsigned short u16;
using frag  = __attribute__((ext_vector_type(8))) short;   // 8 x bf16 (4 VGPRs)
using f32x4 = __attribute__((ext_vector_type(4))) float;

__device__ __forceinline__ void split_bf16(float v, u16& hi, u16& lo) {
    const unsigned u = __float_as_uint(v);
    hi = (u16)(u >> 16);
    const float hf = __uint_as_float((unsigned)hi << 16);
    lo = (u16)(__float_as_uint(v - hf) >> 16);
}

__device__ __forceinline__ unsigned pk2(u16 a, u16 b) {
    return (unsigned)a | ((unsigned)b << 16);
}

__device__ __forceinline__ void split8(const float4& a, const float4& b,
                                       uint4& hi, uint4& lo) {
    u16 h[8], l[8];
    const float f[8] = {a.x, a.y, a.z, a.w, b.x, b.y, b.z, b.w};
#pragma unroll
    for (int i = 0; i < 8; ++i) split_bf16(f[i], h[i], l[i]);
    hi = make_uint4(pk2(h[0], h[1]), pk2(h[2], h[3]), pk2(h[4], h[5]), pk2(h[6], h[7]));
    lo = make_uint4(pk2(l[0], l[1]), pk2(l[2], l[3]), pk2(l[4], l[5]), pk2(l[6], l[7]));
}

// =====================================================================
// K1: qkv split-bf16 MFMA GEMM (register-prefetched) + chunk_sum epilogue
// grid (64 row-tiles, 4 head-pairs) x 256. Block 0 also does rank-1 setup.
// =====================================================================
__global__ __launch_bounds__(256) void qkv_fused(
    const float* __restrict__ x,
    const float* __restrict__ wq, const float* __restrict__ wk, const float* __restrict__ wv,
    const float* __restrict__ bq, const float* __restrict__ bk, const float* __restrict__ bv,
    const float* __restrict__ wg_w, const float* __restrict__ wg_b,
    const float* __restrict__ kvs, const float* __restrict__ qks,
    float* __restrict__ qh, float* __restrict__ kh, float* __restrict__ vh,
    float* __restrict__ simG, float* __restrict__ gG,
    float* __restrict__ ZcT, float* __restrict__ mT, float* __restrict__ sT,
    float* __restrict__ gTt,
    float* __restrict__ aW, float* __restrict__ bW, int* __restrict__ flagW)
{
    constexpr int LDK = 40;     // u16 per staged row
    constexpr int LDT = 68;     // f32 per tile row (272 B, float4-aligned)
    __shared__ __align__(16) float smemf[3 * 64 * LDT];   // staging aliases tiles
    __shared__ __align__(16) float wkT[2 * 1152];         // [h][e*36+d]
    __shared__ float lsim[128], lg2[128];

    u16* As_hi = (u16*)smemf;          // 2560 u16
    u16* As_lo = As_hi + 2560;
    u16* Wst   = As_lo + 2560;         // weight w: hi at w*5120, lo +2560
    float* Qt = smemf;
    float* Kt = Qt + 64 * LDT;
    float* Vt = Kt + 64 * LDT;

    const int tid = threadIdx.x;
    const int mt = blockIdx.x, nt = blockIdx.y;
    const int m0 = mt * 64, ncol0 = nt * 64;
    const int bidx = m0 >> 11, lg = m0 & (Ls - 1);
    const int wave = tid >> 6, lane = tid & 63;
    const int l15 = lane & 15, quad = lane >> 4;
    const int srow = tid >> 2, sk = (tid & 3) * 8;

    for (int i = tid; i < 2048; i += 256) {
        const int h = i >> 10, de = i & 1023;
        const int d = de >> 5, e = de & 31;
        wkT[h * 1152 + e * 36 + d] = wg_w[de] * kvs[(nt * 2 + h) * 1024 + de];
    }

    const float* Wsrc[3] = {wq, wk, wv};
    f32x4 acc[3][4] = {};

    // prefetch iter 0
    float4 a0 = *(const float4*)&x[(size_t)(m0 + srow) * 256 + sk];
    float4 a1 = *(const float4*)&x[(size_t)(m0 + srow) * 256 + sk + 4];
    float4 w0[3], w1[3];
#pragma unroll
    for (int w = 0; w < 3; ++w) {
        w0[w] = *(const float4*)&Wsrc[w][(size_t)(ncol0 + srow) * 256 + sk];
        w1[w] = *(const float4*)&Wsrc[w][(size_t)(ncol0 + srow) * 256 + sk + 4];
    }

    for (int it = 0; it < 8; ++it) {
        __syncthreads();
        {
            uint4 hi, lo;
            split8(a0, a1, hi, lo);
            *(uint4*)&As_hi[srow * LDK + sk] = hi;
            *(uint4*)&As_lo[srow * LDK + sk] = lo;
#pragma unroll
            for (int w = 0; w < 3; ++w) {
                split8(w0[w], w1[w], hi, lo);
                *(uint4*)&Wst[w * 5120 + srow * LDK + sk] = hi;
                *(uint4*)&Wst[w * 5120 + 2560 + srow * LDK + sk] = lo;
            }
        }
        __syncthreads();

        if (it < 7) {   // issue next-iter loads; they fly during MFMA below
            const int k0 = (it + 1) * 32;
            a0 = *(const float4*)&x[(size_t)(m0 + srow) * 256 + k0 + sk];
            a1 = *(const float4*)&x[(size_t)(m0 + srow) * 256 + k0 + sk + 4];
#pragma unroll
            for (int w = 0; w < 3; ++w) {
                w0[w] = *(const float4*)&Wsrc[w][(size_t)(ncol0 + srow) * 256 + k0 + sk];
                w1[w] = *(const float4*)&Wsrc[w][(size_t)(ncol0 + srow) * 256 + k0 + sk + 4];
            }
        }

        frag ah[4], al[4];
#pragma unroll
        for (int tm = 0; tm < 4; ++tm) {
            const int r = tm * 16 + l15;
            ah[tm] = *(const frag*)&As_hi[r * LDK + quad * 8];
            al[tm] = *(const frag*)&As_lo[r * LDK + quad * 8];
        }
#pragma unroll
        for (int w = 0; w < 3; ++w) {
            const u16* bp = &Wst[w * 5120 + (wave * 16 + l15) * LDK + quad * 8];
            const frag bh = *(const frag*)bp;
            const frag bl = *(const frag*)(bp + 2560);
#pragma unroll
            for (int tm = 0; tm < 4; ++tm) {
                acc[w][tm] = __builtin_amdgcn_mfma_f32_16x16x32_bf16(ah[tm], bh, acc[w][tm], 0, 0, 0);
                acc[w][tm] = __builtin_amdgcn_mfma_f32_16x16x32_bf16(ah[tm], bl, acc[w][tm], 0, 0, 0);
                acc[w][tm] = __builtin_amdgcn_mfma_f32_16x16x32_bf16(al[tm], bh, acc[w][tm], 0, 0, 0);
            }
        }
    }
    __syncthreads();   // staging dead; write tiles (aliased region)

    {
        float* tiles[3] = {Qt, Kt, Vt};
        const float* biases[3] = {bq, bk, bv};
#pragma unroll
        for (int w = 0; w < 3; ++w) {
            const int col = wave * 16 + l15;
            const float bias = biases[w][ncol0 + col];
#pragma unroll
            for (int tm = 0; tm < 4; ++tm)
#pragma unroll
                for (int r = 0; r < 4; ++r) {
                    const int m = tm * 16 + quad * 4 + r;
                    tiles[w][m * LDT + col] = acc[w][tm][r] + bias;
                }
        }
    }
    __syncthreads();

    // ---- normalize k,v in place; sim ----
    if (tid < 128) {
        const int h = tid >> 6, l = tid & 63;
        const int rb = l * LDT + h * 32;
        float4 kr[8], vr[8];
        float ksum = 0.f, vsum = 0.f, qk = 0.f;
#pragma unroll
        for (int e4 = 0; e4 < 8; ++e4) {
            kr[e4] = *(const float4*)&Kt[rb + e4 * 4];
            vr[e4] = *(const float4*)&Vt[rb + e4 * 4];
            const float4 q4 = *(const float4*)&Qt[rb + e4 * 4];
            ksum += kr[e4].x * kr[e4].x + kr[e4].y * kr[e4].y + kr[e4].z * kr[e4].z + kr[e4].w * kr[e4].w;
            vsum += vr[e4].x * vr[e4].x + vr[e4].y * vr[e4].y + vr[e4].z * vr[e4].z + vr[e4].w * vr[e4].w;
            qk   += q4.x * kr[e4].x + q4.y * kr[e4].y + q4.z * kr[e4].z + q4.w * kr[e4].w;
        }
        const float kscale = 1.f / fmaxf(sqrtf(ksum), 1e-12f);
        const float vscale = 1.f / fmaxf(sqrtf(vsum), 1e-12f);
#pragma unroll
        for (int e4 = 0; e4 < 8; ++e4) {
            float4 k4 = kr[e4], v4 = vr[e4];
            k4.x *= kscale; k4.y *= kscale; k4.z *= kscale; k4.w *= kscale;
            v4.x *= vscale; v4.y *= vscale; v4.z *= vscale; v4.w *= vscale;
            *(float4*)&Kt[rb + e4 * 4] = k4;
            *(float4*)&Vt[rb + e4 * 4] = v4;
        }
        const float sim = qk * qks[nt * 2 + h];
        lsim[h * 64 + l] = sim;
        simG[(size_t)(bidx * 8 + nt * 2 + h) * Ls + lg + l] = sim;
    }
    __syncthreads();

    // ---- copy q, kn, vn to global ----
    {
        const float* tl[3] = {Qt, Kt, Vt};
        float* gl[3] = {qh, kh, vh};
#pragma unroll
        for (int arr = 0; arr < 3; ++arr)
#pragma unroll
            for (int it = 0; it < 4; ++it) {
                const int idx = it * 1024 + tid * 4;
                const int h = idx >> 11, rem = idx & 2047;
                const int l = rem >> 5, e4 = rem & 31;
                const float4 v = *(const float4*)&tl[arr][l * LDT + h * 32 + e4];
                *(float4*)&gl[arr][(size_t)(bidx * 8 + nt * 2 + h) * 65536 +
                                   (size_t)(lg + l) * 32 + e4] = v;
            }
    }

    // ---- gate per (h,l); 2 threads per task ----
    {
        const int task = tid >> 1, half = tid & 1;
        const int h = task >> 6, l = task & 63;
        float4 vr[8];
#pragma unroll
        for (int d4 = 0; d4 < 8; ++d4)
            vr[d4] = *(const float4*)&Vt[l * LDT + h * 32 + d4 * 4];
        float u = 0.f;
        const int e0 = half * 16;
#pragma unroll 4
        for (int e = e0; e < e0 + 16; ++e) {
            float4 s4 = make_float4(0.f, 0.f, 0.f, 0.f);
#pragma unroll
            for (int d4 = 0; d4 < 8; ++d4) {
                const float4 w4 = *(const float4*)&wkT[h * 1152 + e * 36 + d4 * 4];
                s4.x = fmaf(vr[d4].x, w4.x, s4.x);
                s4.y = fmaf(vr[d4].y, w4.y, s4.y);
                s4.z = fmaf(vr[d4].z, w4.z, s4.z);
                s4.w = fmaf(vr[d4].w, w4.w, s4.w);
            }
            u = fmaf(s4.x + s4.y + s4.z + s4.w, Kt[l * LDT + h * 32 + e], u);
        }
        u += __shfl_xor(u, 1);
        if (half == 0) {
            const float r = fmaxf(u + wg_b[0], 0.f);
            const float g = r * r + EPSV;
            lg2[h * 64 + l] = g;
            gG[(size_t)(bidx * 8 + nt * 2 + h) * Ls + lg + l] = g;
        }
    }
    __syncthreads();

    // ---- chunk-Z totals ----
    {
        const int d = tid >> 3, e4m = (tid & 7) * 4;
#pragma unroll
        for (int h = 0; h < 2; ++h)
#pragma unroll
            for (int cc = 0; cc < 2; ++cc) {
                float4 z4 = make_float4(0.f, 0.f, 0.f, 0.f);
#pragma unroll 8
                for (int l = 0; l < 32; ++l) {
                    const int lr = cc * 32 + l;
                    const float gv = lg2[h * 64 + lr] * Vt[lr * LDT + h * 32 + d];
                    const float4 k4 = *(const float4*)&Kt[lr * LDT + h * 32 + e4m];
                    z4.x = fmaf(gv, k4.x, z4.x);
                    z4.y = fmaf(gv, k4.y, z4.y);
                    z4.z = fmaf(gv, k4.z, z4.z);
                    z4.w = fmaf(gv, k4.w, z4.w);
                }
                const int bhg = bidx * 8 + nt * 2 + h;
                const int cg = (lg >> 5) + cc;
                *(float4*)&ZcT[((size_t)bhg * NCH + cg) * 1024 + d * 32 + e4m] = z4;
            }
    }

    // ---- (m,s,g) raw chunk totals ----
    {
        const int h = wave >> 1, cc = wave & 1;
        if (lane < 32) {
            const int lr = cc * 32 + lane;
            float m = lsim[h * 64 + lr], s = 1.f, g = lg2[h * 64 + lr];
#pragma unroll
            for (int off = 16; off; off >>= 1) {
                const float mo = __shfl_xor(m, off);
                const float so = __shfl_xor(s, off);
                const float mn = fmaxf(m, mo);
                s = s * __expf(m - mn) + so * __expf(mo - mn);
                m = mn;
                g += __shfl_xor(g, off);
            }
            if (lane == 0) {
                const int bhg = bidx * 8 + nt * 2 + h;
                const int cg = (lg >> 5) + cc;
                mT[bhg * NCH + cg] = m;
                sT[bhg * NCH + cg] = s;
                gTt[bhg * NCH + cg] = g;
            }
        }
    }

    // ---- rank-1 kvs setup (block 0 only) ----
    if (mt == 0 && nt == 0) {
        const int h = tid >> 5, e = tid & 31;
        const float* K = kvs + h * 1024;
        const float k00 = K[0];
        int ok = (k00 != 0.0f);
        for (int d = 0; d < 32; ++d) {
            const float lhs = K[d * 32 + e] * k00;
            const float rhs = K[d * 32] * K[e];
            const float diff = fabsf(lhs - rhs);
            if (diff > 1e-6f * fmaxf(fmaxf(fabsf(lhs), fabsf(rhs)), 1e-20f)) ok = 0;
        }
        aW[h * 32 + e] = K[e * 32];
        bW[h * 32 + e] = (k00 != 0.0f) ? K[e] / k00 : 0.f;
        const int allok = __syncthreads_and(ok);
        if (tid == 0) flagW[0] = allok;
    }
}

// =====================================================================
// K2: prefix — Hillis-Steele scan of Z chunk totals in LDS (exclusive, in place)
// grid (16 bh, 16 seg) x 256. Reads/writes 4 MB once.
// =====================================================================
__global__ __launch_bounds__(256) void prefix_kernel(float* __restrict__ Zc)
{
    __shared__ float sc[64 * 64];
    const int bh = blockIdx.x, seg = blockIdx.y;
    const int tid = threadIdx.x;
    float* Zb = Zc + (size_t)bh * NCH * 1024 + seg * 64;

#pragma unroll
    for (int it = 0; it < 16; ++it) {
        const int idx = it * 256 + tid;
        const int cc = idx >> 6, e = idx & 63;
        sc[idx] = Zb[(size_t)cc * 1024 + e];
    }
    __syncthreads();
#pragma unroll
    for (int st = 1; st < 64; st <<= 1) {
        float tmp[16];
#pragma unroll
        for (int it = 0; it < 16; ++it) {
            const int idx = it * 256 + tid;
            tmp[it] = ((idx >> 6) >= st) ? sc[idx - st * 64] : 0.f;
        }
        __syncthreads();
#pragma unroll
        for (int it = 0; it < 16; ++it) sc[it * 256 + tid] += tmp[it];
        __syncthreads();
    }
#pragma unroll
    for (int it = 0; it < 16; ++it) {
        const int idx = it * 256 + tid;
        const int cc = idx >> 6, e = idx & 63;
        Zb[(size_t)cc * 1024 + e] = cc ? sc[idx - 64] : 0.f;   // exclusive
    }
}

// =====================================================================
// K3: chunk_out — reads precomputed Z prefix tile; (m,s,g) wave64 scan inline
// grid (NCH=64, 16 bh) x 256 threads
// =====================================================================
__global__ __launch_bounds__(256) void chunk_out_kernel(
    const float* __restrict__ qh, const float* __restrict__ knG, const float* __restrict__ vnG,
    const float* __restrict__ simG, const float* __restrict__ gG,
    const float* __restrict__ kvs,
    const float* __restrict__ ZcP, const float* __restrict__ mT,
    const float* __restrict__ sT, const float* __restrict__ gTt,
    const float* __restrict__ aW, const float* __restrict__ bW,
    const int* __restrict__ flagW,
    u16* __restrict__ chi, u16* __restrict__ clo)
{
    __shared__ __align__(16) float qa[1024], knb[1024], zp[1024], sW[1024];
    __shared__ __align__(16) float vnT[32 * 36];   // [d][j]
    __shared__ float lkvs[1024];                    // fallback only
    __shared__ float lgS[32], lsimS[32], lwgt[32];
    const int tid = threadIdx.x;
    const int c = blockIdx.x, bh = blockIdx.y, h = bh & 7, b = bh >> 3;
    const int l = tid >> 3, e4 = (tid & 7) * 4;
    const size_t base4 = ((size_t)bh * Ls + (size_t)c * T) * 8 + tid;   // float4 idx
    const int flag = flagW[0];

    const float4 qv4 = ((const float4*)qh)[base4];
    const float4 kn4 = ((const float4*)knG)[base4];
    const float4 vn4 = ((const float4*)vnG)[base4];
    const float4 z4  = ((const float4*)ZcP)[((size_t)bh * NCH + c) * 256 + tid];
    const float4 la4 = *(const float4*)&aW[h * 32 + e4];
    const float4 lb4 = *(const float4*)&bW[h * 32 + e4];
    if (tid < 32) {
        lgS[tid] = gG[bh * Ls + c * T + tid];
        lsimS[tid] = simG[bh * Ls + c * T + tid];
    }
    if (!flag) {
        *(float4*)&lkvs[tid * 4] = *(const float4*)&kvs[h * 1024 + tid * 4];
    }
    {
        float4 q = qv4, k = kn4;
        if (flag) {
            q.x *= la4.x; q.y *= la4.y; q.z *= la4.z; q.w *= la4.w;
            k.x *= lb4.x; k.y *= lb4.y; k.z *= lb4.z; k.w *= lb4.w;
        }
        *(float4*)&qa[l * 32 + e4] = q;
        *(float4*)&knb[l * 32 + e4] = k;
        *(float4*)&zp[tid * 4] = z4;
        vnT[(e4 + 0) * 36 + l] = vn4.x;
        vnT[(e4 + 1) * 36 + l] = vn4.y;
        vnT[(e4 + 2) * 36 + l] = vn4.z;
        vnT[(e4 + 3) * 36 + l] = vn4.w;
    }
    __syncthreads();

    if (tid < 64) {
        // chunk-level (m,s,g) prefix: inclusive wave64 scan of raw totals, pick c-1
        float mC = mT[bh * NCH + tid], sC = sT[bh * NCH + tid], gC = gTt[bh * NCH + tid];
#pragma unroll
        for (int off = 1; off < 64; off <<= 1) {
            const float mo = __shfl_up(mC, off);
            const float so = __shfl_up(sC, off);
            const float go = __shfl_up(gC, off);
            if (tid >= off) {
                const float mn = fmaxf(mC, mo);
                sC = sC * __expf(mC - mn) + so * __expf(mo - mn);
                mC = mn;
                gC += go;
            }
        }
        const float mp = (c > 0) ? __shfl(mC, c - 1) : -1e30f;
        const float sp = (c > 0) ? __shfl(sC, c - 1) : 0.f;
        const float gp = (c > 0) ? __shfl(gC, c - 1) : 0.f;

        if (tid < 32) {
            float m = lsimS[tid], s = 1.f, g = lgS[tid];
#pragma unroll
            for (int off = 1; off < 32; off <<= 1) {
                const float mo = __shfl_up(m, off);
                const float so = __shfl_up(s, off);
                const float go = __shfl_up(g, off);
                if (tid >= off) {
                    const float mn = fmaxf(m, mo);
                    s = s * __expf(m - mn) + so * __expf(mo - mn);
                    m = mn;
                    g += go;
                }
            }
            const float mn = fmaxf(mp, m);
            s = sp * __expf(mp - mn) + s * __expf(m - mn);
            m = mn;
            g += gp;
            const float sw = __expf(lsimS[tid] - m) / (s + EPSV);
            const float sig = 1.f / (1.f + __expf(-sw));
            lwgt[tid] = (1.f + sw * sig) / (g + EPSV);
        }
    }

    float4 y4 = make_float4(0.f, 0.f, 0.f, 0.f);
    if (flag) {
        float qrow[32];
#pragma unroll
        for (int d4 = 0; d4 < 8; ++d4)
            *(float4*)&qrow[d4 * 4] = *(const float4*)&qa[l * 32 + d4 * 4];
        float4 s4 = make_float4(0.f, 0.f, 0.f, 0.f);
#pragma unroll 8
        for (int d = 0; d < 32; ++d) {
            const float qd = qrow[d];
            const float4 v4 = *(const float4*)&vnT[d * 36 + e4];
            const float4 p4 = *(const float4*)&zp[d * 32 + e4];
            s4.x = fmaf(qd, v4.x, s4.x);
            s4.y = fmaf(qd, v4.y, s4.y);
            s4.z = fmaf(qd, v4.z, s4.z);
            s4.w = fmaf(qd, v4.w, s4.w);
            y4.x = fmaf(qd, p4.x, y4.x);
            y4.y = fmaf(qd, p4.y, y4.y);
            y4.z = fmaf(qd, p4.z, y4.z);
            y4.w = fmaf(qd, p4.w, y4.w);
        }
        y4.x *= lb4.x; y4.y *= lb4.y; y4.z *= lb4.z; y4.w *= lb4.w;
        const float4 lg4 = *(const float4*)&lgS[e4];
        float4 sm;
        sm.x = (e4 + 0 <= l) ? lg4.x * s4.x : 0.f;
        sm.y = (e4 + 1 <= l) ? lg4.y * s4.y : 0.f;
        sm.z = (e4 + 2 <= l) ? lg4.z * s4.z : 0.f;
        sm.w = (e4 + 3 <= l) ? lg4.w * s4.w : 0.f;
        *(float4*)&sW[l * 32 + e4] = sm;
        __syncthreads();
        float srow[32];
#pragma unroll
        for (int j4 = 0; j4 < 8; ++j4)
            *(float4*)&srow[j4 * 4] = *(const float4*)&sW[l * 32 + j4 * 4];
#pragma unroll 8
        for (int j = 0; j < 32; ++j) {
            const float sj = srow[j];
            const float4 k4 = *(const float4*)&knb[j * 32 + e4];
            y4.x = fmaf(sj, k4.x, y4.x);
            y4.y = fmaf(sj, k4.y, y4.y);
            y4.z = fmaf(sj, k4.z, y4.z);
            y4.w = fmaf(sj, k4.w, y4.w);
        }
    } else {
        __syncthreads();
        float* yp = &y4.x;
#pragma unroll
        for (int ii = 0; ii < 4; ++ii) {
            const int e = e4 + ii;
            float qe[32];
#pragma unroll
            for (int d = 0; d < 32; ++d)
                qe[d] = qa[l * 32 + d] * lkvs[d * 32 + e];
            float y = 0.f;
#pragma unroll
            for (int d = 0; d < 32; ++d)
                y = fmaf(qe[d], zp[d * 32 + e], y);
            for (int j = 0; j < 32; ++j) {
                float s = 0.f;
#pragma unroll
                for (int d = 0; d < 32; ++d)
                    s = fmaf(qe[d], vnT[d * 36 + j], s);
                if (j <= l) y = fmaf(lgS[j] * s, knb[j * 32 + e], y);
            }
            yp[ii] = y;
        }
    }
    const float w = lwgt[l];
    ushort4 hi4, lo4;
    split_bf16(y4.x * w, hi4.x, lo4.x);
    split_bf16(y4.y * w, hi4.y, lo4.y);
    split_bf16(y4.z * w, hi4.z, lo4.z);
    split_bf16(y4.w * w, hi4.w, lo4.w);
    const size_t oidx = ((size_t)(b * Ls + c * T + l)) * 256 + h * 32 + e4;
    *(ushort4*)&chi[oidx] = hi4;
    *(ushort4*)&clo[oidx] = lo4;
}

// =====================================================================
// K4: out-proj GEMM, register-prefetched; W split on the fly
// grid (64, 4) x 256
// =====================================================================
__global__ __launch_bounds__(256) void out_gemm(
    const u16* __restrict__ Ahi, const u16* __restrict__ Alo,
    const float* __restrict__ wo, const float* __restrict__ bo,
    float* __restrict__ out)
{
    constexpr int LDK = 40;
    __shared__ __align__(16) u16 As_hi[64 * LDK];
    __shared__ __align__(16) u16 As_lo[64 * LDK];
    __shared__ __align__(16) u16 Ws_hi[64 * LDK];
    __shared__ __align__(16) u16 Ws_lo[64 * LDK];

    const int tid = threadIdx.x;
    const int mt = blockIdx.x, nt = blockIdx.y;
    const int m0 = mt * 64, ncol0 = nt * 64;
    const int wave = tid >> 6, lane = tid & 63;
    const int l15 = lane & 15, quad = lane >> 4;
    const int srow = tid >> 2, sk = (tid & 3) * 8;

    f32x4 acc[4] = {};

    uint4 ah = *(const uint4*)&Ahi[(size_t)(m0 + srow) * 256 + sk];
    uint4 al = *(const uint4*)&Alo[(size_t)(m0 + srow) * 256 + sk];
    float4 w0 = *(const float4*)&wo[(size_t)(ncol0 + srow) * 256 + sk];
    float4 w1 = *(const float4*)&wo[(size_t)(ncol0 + srow) * 256 + sk + 4];

    for (int it = 0; it < 8; ++it) {
        __syncthreads();
        {
            uint4 whi, wlo;
            split8(w0, w1, whi, wlo);
            *(uint4*)&As_hi[srow * LDK + sk] = ah;
            *(uint4*)&As_lo[srow * LDK + sk] = al;
            *(uint4*)&Ws_hi[srow * LDK + sk] = whi;
            *(uint4*)&Ws_lo[srow * LDK + sk] = wlo;
        }
        __syncthreads();

        if (it < 7) {
            const int k0 = (it + 1) * 32;
            ah = *(const uint4*)&Ahi[(size_t)(m0 + srow) * 256 + k0 + sk];
            al = *(const uint4*)&Alo[(size_t)(m0 + srow) * 256 + k0 + sk];
            w0 = *(const float4*)&wo[(size_t)(ncol0 + srow) * 256 + k0 + sk];
            w1 = *(const float4*)&wo[(size_t)(ncol0 + srow) * 256 + k0 + sk + 4];
        }

        const frag fah = *(const frag*)&As_hi[(wave * 16 + l15) * LDK + quad * 8];
        const frag fal = *(const frag*)&As_lo[(wave * 16 + l15) * LDK + quad * 8];
#pragma unroll
        for (int cf = 0; cf < 4; ++cf) {
            const frag fbh = *(const frag*)&Ws_hi[(cf * 16 + l15) * LDK + quad * 8];
            const frag fbl = *(const frag*)&Ws_lo[(cf * 16 + l15) * LDK + quad * 8];
            acc[cf] = __builtin_amdgcn_mfma_f32_16x16x32_bf16(fah, fbh, acc[cf], 0, 0, 0);
            acc[cf] = __builtin_amdgcn_mfma_f32_16x16x32_bf16(fah, fbl, acc[cf], 0, 0, 0);
            acc[cf] = __builtin_amdgcn_mfma_f32_16x16x32_bf16(fal, fbh, acc[cf], 0, 0, 0);
        }
    }

#pragma unroll
    for (int cf = 0; cf < 4; ++cf) {
        const int o = ncol0 + cf * 16 + l15;
        const float bias = bo[o];
#pragma unroll
        for (int r = 0; r < 4; ++r) {
            const int rm = m0 + wave * 16 + quad * 4 + r;
            out[(size_t)rm * 256 + o] = acc[cf][r] + bias;
        }
    }
}

extern "C" void kernel_launch(void* const* d_in, const int* in_sizes, int n_in,
                              void* d_out, int out_size, void* d_ws, size_t ws_size,
                              hipStream_t stream) {
    const float* x    = (const float*)d_in[0];
    const float* wq_w = (const float*)d_in[1];
    const float* wq_b = (const float*)d_in[2];
    const float* wk_w = (const float*)d_in[3];
    const float* wk_b = (const float*)d_in[4];
    const float* wv_w = (const float*)d_in[5];
    const float* wv_b = (const float*)d_in[6];
    const float* wo_w = (const float*)d_in[7];
    const float* wo_b = (const float*)d_in[8];
    const float* wg_w = (const float*)d_in[9];
    const float* wg_b = (const float*)d_in[10];
    const float* kvs  = (const float*)d_in[11];
    const float* qks  = (const float*)d_in[12];
    float* out = (float*)d_out;

    u16* chi = (u16*)d_ws;                 // 1048576 u16
    u16* clo = chi + 1048576;              // 1048576 u16
    float* qh   = (float*)(clo + 1048576); // fp32 region
    float* kh   = qh + 1048576;
    float* vh   = kh + 1048576;
    float* ZcT  = vh + 1048576;            // 1048576
    float* simG = ZcT + 1048576;           // 32768
    float* gG   = simG + 32768;            // 32768
    float* mT   = gG + 32768;              // 1024
    float* sT   = mT + 1024;
    float* gTt  = sT + 1024;
    float* aW   = gTt + 1024;              // 256
    float* bW   = aW + 256;                // 256
    int* flagW  = (int*)(bW + 256);

    qkv_fused<<<dim3(64, 4), 256, 0, stream>>>(
        x, wq_w, wk_w, wv_w, wq_b, wk_b, wv_b, wg_w, wg_b, kvs, qks,
        qh, kh, vh, simG, gG, ZcT, mT, sT, gTt, aW, bW, flagW);
    prefix_kernel<<<dim3(16, 16), 256, 0, stream>>>(ZcT);
    chunk_out_kernel<<<dim3(NCH, 16), 256, 0, stream>>>(
        qh, kh, vh, simG, gG, kvs, ZcT, mT, sT, gTt, aW, bW, flagW, chi, clo);
    out_gemm<<<dim3(64, 4), 256, 0, stream>>>(
        chi, clo, wo_w, wo_b, out);
}